// Round 9
// baseline (80.958 us; speedup 1.0000x reference)
//
#include <hip/hip_runtime.h>

// Complex BatchNorm (training whitening), z:[B=32, N=C*H*W, 2] fp32.
// Two-kernel split to break the per-thread load->stats->store serial chain:
//   K1 (stats): pure read-reduce. One thread per float2 column; 32 streaming
//      loads -> 5 moments -> fused 2x2 matrix (gamma folded) + offset
//      (beta - C*mu) written to d_ws (cached; K2 re-reads from L2/L3).
//   K2 (apply): pure streaming map. Thread = (batch-quarter, float4 column);
//      wave accesses are contiguous 1KB segments; nontemporal stores protect
//      the input's L3 residency so K1's reads stay L3-hits across replays.
// Fallback single-pass kernel if ws_size is too small.

constexpr int BATCH = 32;

typedef float f32x4 __attribute__((ext_vector_type(4)));

// ---------------- K1: per-column stats -> fused matrix ----------------
__global__ __launch_bounds__(256) void cbn_stats(
    const float2* __restrict__ z,
    const float* __restrict__ gamma,
    const float* __restrict__ beta,
    float4* __restrict__ cmat,   // [N]: (c00, c10, c01, c11)
    float2* __restrict__ coff,   // [N]: (d0, d1) = beta - C*mu
    int N)
{
    int n = blockIdx.x * blockDim.x + threadIdx.x;
    if (n >= N) return;

    float sx = 0.f, sy = 0.f, sxx = 0.f, sxy = 0.f, syy = 0.f;
#pragma unroll
    for (int b = 0; b < BATCH; ++b) {
        float2 q = z[(size_t)b * N + n];
        sx += q.x; sy += q.y;
        sxx = fmaf(q.x, q.x, sxx);
        sxy = fmaf(q.x, q.y, sxy);
        syy = fmaf(q.y, q.y, syy);
    }

    const float invB  = 1.0f / BATCH;
    const float invB1 = 1.0f / (BATCH - 1);

    float mx = sx * invB, my = sy * invB;
    float cxx = (sxx - BATCH * mx * mx) * invB1;
    float cxy = (sxy - BATCH * mx * my) * invB1;
    float cyy = (syy - BATCH * my * my) * invB1;

    float s  = sqrtf(cxx * cyy - cxy * cxy);
    float rt = 1.0f / sqrtf(cxx + cyy + 2.0f * s);
    float a00 = (cxx + s) * rt;
    float a01 = cxy * rt;            // symmetric
    float a11 = (cyy + s) * rt;

    const float g00 = gamma[0], g01 = gamma[1], g10 = gamma[2], g11 = gamma[3];
    const float be0 = beta[0], be1 = beta[1];

    float c00 = g00 * a00 + g01 * a01;
    float c01 = g00 * a01 + g01 * a11;
    float c10 = g10 * a00 + g11 * a01;
    float c11 = g10 * a01 + g11 * a11;

    float d0 = be0 - c00 * mx - c01 * my;
    float d1 = be1 - c10 * mx - c11 * my;

    cmat[n] = make_float4(c00, c10, c01, c11);
    coff[n] = make_float2(d0, d1);
}

// ---------------- K2: streaming apply ----------------
__global__ __launch_bounds__(256) void cbn_apply(
    const float4* __restrict__ z4,
    const float4* __restrict__ cmat,   // [N] as float4
    const float4* __restrict__ coff4,  // [N/2] float2-pairs as float4
    float4* __restrict__ out4,
    int N2)   // float4 columns (= N/2)
{
    int t = blockIdx.x * blockDim.x + threadIdx.x;
    int g = t >> 18;            // batch quarter 0..3 (N2 = 2^18)
    int c = t & (N2 - 1);       // float4 column; contiguous per wave

    float4 m0 = cmat[2 * c];        // pos0 matrix
    float4 m1 = cmat[2 * c + 1];    // pos1 matrix
    float4 d  = coff4[c];           // (d0,d1) pos0, (d0,d1) pos1

#pragma unroll
    for (int k = 0; k < 8; ++k) {
        int b = g * 8 + k;
        float4 q = z4[(size_t)b * N2 + c];
        f32x4 o;
        o.x = fmaf(m0.x, q.x, fmaf(m0.z, q.y, d.x));
        o.y = fmaf(m0.y, q.x, fmaf(m0.w, q.y, d.y));
        o.z = fmaf(m1.x, q.z, fmaf(m1.z, q.w, d.z));
        o.w = fmaf(m1.y, q.z, fmaf(m1.w, q.w, d.w));
        __builtin_nontemporal_store(o, (f32x4*)&out4[(size_t)b * N2 + c]);
    }
}

// ---------------- fallback: single-pass (R6, known-good) ----------------
typedef float f32x2 __attribute__((ext_vector_type(2)));

__global__ __launch_bounds__(256) void cbn_fallback(
    const float2* __restrict__ z,
    const float* __restrict__ gamma,
    const float* __restrict__ beta,
    float2* __restrict__ out,
    int N)
{
    int n = blockIdx.x * blockDim.x + threadIdx.x;
    if (n >= N) return;

    float2 v[BATCH];
#pragma unroll
    for (int b = 0; b < BATCH; ++b) v[b] = z[(size_t)b * N + n];
#pragma unroll
    for (int b = 0; b < BATCH; ++b)
        asm volatile("" : "+v"(v[b].x), "+v"(v[b].y));

    float sx = 0.f, sy = 0.f, sxx = 0.f, sxy = 0.f, syy = 0.f;
#pragma unroll
    for (int b = 0; b < BATCH; ++b) {
        float2 q = v[b];
        sx += q.x; sy += q.y;
        sxx = fmaf(q.x, q.x, sxx);
        sxy = fmaf(q.x, q.y, sxy);
        syy = fmaf(q.y, q.y, syy);
    }
    const float invB = 1.0f / BATCH, invB1 = 1.0f / (BATCH - 1);
    float mx = sx * invB, my = sy * invB;
    float cxx = (sxx - BATCH * mx * mx) * invB1;
    float cxy = (sxy - BATCH * mx * my) * invB1;
    float cyy = (syy - BATCH * my * my) * invB1;
    float s  = sqrtf(cxx * cyy - cxy * cxy);
    float rt = 1.0f / sqrtf(cxx + cyy + 2.0f * s);
    float a00 = (cxx + s) * rt, a01 = cxy * rt, a11 = (cyy + s) * rt;
    const float g00 = gamma[0], g01 = gamma[1], g10 = gamma[2], g11 = gamma[3];
    const float be0 = beta[0], be1 = beta[1];
    float c00 = g00 * a00 + g01 * a01;
    float c01 = g00 * a01 + g01 * a11;
    float c10 = g10 * a00 + g11 * a01;
    float c11 = g10 * a01 + g11 * a11;
#pragma unroll
    for (int b = 0; b < BATCH; ++b) {
        float dx = v[b].x - mx, dy = v[b].y - my;
        f32x2 o;
        o.x = fmaf(c00, dx, fmaf(c01, dy, be0));
        o.y = fmaf(c10, dx, fmaf(c11, dy, be1));
        __builtin_nontemporal_store(o, (f32x2*)&out[(size_t)b * N + n]);
    }
}

extern "C" void kernel_launch(void* const* d_in, const int* in_sizes, int n_in,
                              void* d_out, int out_size, void* d_ws, size_t ws_size,
                              hipStream_t stream) {
    const float* z     = (const float*)d_in[0];
    const float* gamma = (const float*)d_in[1];
    const float* beta  = (const float*)d_in[2];

    int N  = in_sizes[0] / (BATCH * 2);   // 524288
    int N2 = N / 2;                       // 262144 (power of two)

    size_t need = (size_t)N * 16 + (size_t)N * 8;   // cmat + coff = 12.6 MB

    if (ws_size >= need && (N2 & (N2 - 1)) == 0) {
        float4* cmat = (float4*)d_ws;
        float2* coff = (float2*)((char*)d_ws + (size_t)N * 16);

        dim3 block(256);
        dim3 grid1((N + 255) / 256);
        hipLaunchKernelGGL(cbn_stats, grid1, block, 0, stream,
                           (const float2*)z, gamma, beta, cmat, coff, N);

        dim3 grid2((unsigned)(((size_t)N2 * 4) / 256));
        hipLaunchKernelGGL(cbn_apply, grid2, block, 0, stream,
                           (const float4*)z, (const float4*)cmat,
                           (const float4*)coff, (float4*)d_out, N2);
    } else {
        dim3 block(256);
        dim3 grid((N + 255) / 256);
        hipLaunchKernelGGL(cbn_fallback, grid, block, 0, stream,
                           (const float2*)z, gamma, beta, (float2*)d_out, N);
    }
}